// Round 1
// 241.743 us; speedup vs baseline: 1.2008x; 1.2008x over previous
//
#include <hip/hip_runtime.h>
#include <cstdint>

namespace {
constexpr int B = 8, C = 3, H = 1024, W = 1024;
constexpr int HO = 256, WO = 256, K2 = 9;
constexpr int HP = H + 2, WP = W + 2;
constexpr int HW = H * W, HOWO = HO * WO;

// Output tile per block: 32 wide x 16 tall, 512 threads (1 output each).
constexpr int TW = 32, TH = 16;
constexpr int NTX = WO / TW;            // 8 tiles in x
constexpr int NTY = HO / TH;            // 16 tiles in y
constexpr int OF = 12;                  // halo px = 3 sigma of 4*N(0,1) offsets
constexpr int WINW = 4 * TW + 2 * OF;   // 152
constexpr int WINH = 4 * TH + 2 * OF;   // 88
constexpr int WPX = WINW * WINH;        // 13376 px
constexpr size_t LDS_BYTES = (size_t)WPX * 12;  // 160512 B <= 163840 (160 KiB/CU)

__device__ __forceinline__ int reflect_src(int p, int n) {
    // padded index p in [0, n+1] -> source index in [0, n-1] (numpy 'reflect')
    int s = p - 1;
    s = (s < 0) ? -s : s;
    s = (s >= n) ? (2 * n - 2 - s) : s;
    return s;
}

// Single fused kernel: stage the tile's reflect-padded sampling window into
// LDS with coalesced reads from the ORIGINAL CHW planes (relayout kernel is
// gone), then serve all 36 divergent bilinear corner reads per thread from
// the LDS pipe instead of the L1/TA (which was costing ~229 cy per gather).
__global__ __launch_bounds__(512) void ds_tiled(
    const float* __restrict__ img,
    const float* __restrict__ kern,
    const float* __restrict__ offh,
    const float* __restrict__ offv,
    const float* __restrict__ ou_p,
    float* __restrict__ out) {
    extern __shared__ unsigned char smem[];
    float2* __restrict__ lA = (float2*)smem;                      // (c0,c1) 8B/px
    float*  __restrict__ lB = (float*)(smem + (size_t)WPX * 8);   // c2      4B/px

    const int b   = blockIdx.x & 7;      // XCD swizzle: one image per XCD
    const int tid = threadIdx.x;
    const int t   = blockIdx.x >> 3;     // 0..127: tile index within image
    const int w0  = (t & (NTX - 1)) * TW;
    const int h0  = (t >> 3) * TH;
    const int X0  = 4 * w0 - (OF - 1);   // window origin in padded coords
    const int Y0  = 4 * h0 - (OF - 1);

    const float* __restrict__ p0 = img + (size_t)b * (C * HW);
    const float* __restrict__ p1 = p0 + HW;
    const float* __restrict__ p2 = p1 + HW;

    // ---- stage window: padded coords [Y0,Y0+WINH) x [X0,X0+WINW) ----
    for (int i = tid; i < WPX; i += 512) {
        int yy = i / WINW;
        int xx = i - yy * WINW;
        int Yp = min(max(Y0 + yy, 0), HP - 1);  // out-of-range slots are never read
        int Xp = min(max(X0 + xx, 0), WP - 1);
        int sy = reflect_src(Yp, H);
        int sx = reflect_src(Xp, W);
        size_t si = (size_t)sy * W + sx;
        lA[i] = make_float2(p0[si], p1[si]);
        lB[i] = p2[si];
    }
    __syncthreads();

    const int lw = tid & (TW - 1);
    const int lh = tid >> 5;
    const int h = h0 + lh, w = w0 + lw;
    const float ou = ou_p[0];
    const float cy = (h + 0.5f) * 4.0f - 0.5f;
    const float cx = (w + 0.5f) * 4.0f - 0.5f;
    const size_t pb = ((size_t)b * K2) * (size_t)HOWO + (size_t)h * WO + w;

    float acc0 = 0.f, acc1 = 0.f, acc2 = 0.f;

#pragma unroll
    for (int k = 0; k < K2; ++k) {
        size_t o = pb + (size_t)(k * HOWO);
        float kv = kern[o];
        float py = cy + (float)(k / 3) + offv[o] * ou;
        float px = cx + (float)(k % 3) + offh[o] * ou;

        float y0f = floorf(py), x0f = floorf(px);
        float bb = py - y0f;
        float aa = px - x0f;

        int y0 = min(max((int)y0f, 0), HP - 1);
        int x0 = min(max((int)x0f, 0), WP - 1);
        int y1 = min(y0 + 1, HP - 1);
        int x1 = min(x0 + 1, WP - 1);

        float v00x, v00y, v00z, v01x, v01y, v01z;
        float v10x, v10y, v10z, v11x, v11y, v11z;

        bool inw = (y0 >= Y0) & (y1 <= Y0 + WINH - 1) &
                   (x0 >= X0) & (x1 <= X0 + WINW - 1);
        if (__builtin_expect(inw, 1)) {
            int i00 = (y0 - Y0) * WINW + (x0 - X0);
            int dx  = x1 - x0;               // 1, or 0 at a clamped edge
            int dyr = (y1 - y0) * WINW;
            int i01 = i00 + dx, i10 = i00 + dyr, i11 = i00 + dyr + dx;
            float2 a;
            a = lA[i00]; v00x = a.x; v00y = a.y; v00z = lB[i00];
            a = lA[i01]; v01x = a.x; v01y = a.y; v01z = lB[i01];
            a = lA[i10]; v10x = a.x; v10y = a.y; v10z = lB[i10];
            a = lA[i11]; v11x = a.x; v11y = a.y; v11z = lB[i11];
        } else {
            // Rare (~3e-4 of taps): |offset| beyond the staged halo.
            // Exact replay of the verified global reflect path.
            int sy0 = reflect_src(y0, H), sy1 = reflect_src(y1, H);
            int sx0 = reflect_src(x0, W), sx1 = reflect_src(x1, W);
            size_t i0 = (size_t)sy0 * W + sx0, i1 = (size_t)sy0 * W + sx1;
            size_t i2 = (size_t)sy1 * W + sx0, i3 = (size_t)sy1 * W + sx1;
            v00x = p0[i0]; v00y = p1[i0]; v00z = p2[i0];
            v01x = p0[i1]; v01y = p1[i1]; v01z = p2[i1];
            v10x = p0[i2]; v10y = p1[i2]; v10z = p2[i2];
            v11x = p0[i3]; v11y = p1[i3]; v11z = p2[i3];
        }

        float tx_, tu_;
        tx_ = v00x + aa * (v01x - v00x);
        tu_ = v10x + aa * (v11x - v10x);
        acc0 += kv * (tx_ + bb * (tu_ - tx_));
        tx_ = v00y + aa * (v01y - v00y);
        tu_ = v10y + aa * (v11y - v10y);
        acc1 += kv * (tx_ + bb * (tu_ - tx_));
        tx_ = v00z + aa * (v01z - v00z);
        tu_ = v10z + aa * (v11z - v10z);
        acc2 += kv * (tx_ + bb * (tu_ - tx_));
    }

    size_t obase = ((size_t)b * C) * (size_t)HOWO + (size_t)h * WO + w;
    out[obase] = acc0;
    out[obase + (size_t)HOWO] = acc1;
    out[obase + (size_t)(2 * HOWO)] = acc2;
}
} // namespace

extern "C" void kernel_launch(void* const* d_in, const int* in_sizes, int n_in,
                              void* d_out, int out_size, void* d_ws, size_t ws_size,
                              hipStream_t stream) {
    const float* img  = (const float*)d_in[0];
    const float* kern = (const float*)d_in[1];
    const float* offh = (const float*)d_in[2];
    const float* offv = (const float*)d_in[3];
    const float* ou   = (const float*)d_in[4];
    float* out = (float*)d_out;

    // Opt-in to >64 KiB dynamic LDS (host-side attr set, graph-capture safe).
    static bool attr_set = false;
    if (!attr_set) {
        hipFuncSetAttribute(reinterpret_cast<const void*>(&ds_tiled),
                            hipFuncAttributeMaxDynamicSharedMemorySize,
                            (int)LDS_BYTES);
        attr_set = true;
    }

    hipLaunchKernelGGL(ds_tiled, dim3(B * NTX * NTY), dim3(512), LDS_BYTES,
                       stream, img, kern, offh, offv, ou, out);
}